// Round 4
// baseline (599.766 us; speedup 1.0000x reference)
//
#include <hip/hip_runtime.h>
#include <hip/hip_cooperative_groups.h>
#include <cstdint>

namespace cg = cooperative_groups;

#define B_ 64
#define M_ 1024
#define F_ 4
#define E_ 256
#define NW_ 32000
#define PL_ 128

// output element offsets (fp32 elements)
#define P_OFF   0
#define PV_OFF  65536
#define PR_OFF  2113536
#define H_OFF   2179072

typedef unsigned short u16;
typedef unsigned int u32;

typedef __bf16 bf16x8 __attribute__((ext_vector_type(8)));
typedef float f32x4 __attribute__((ext_vector_type(4)));

__device__ __forceinline__ u16 f2bf(float f) {
    u32 x = __builtin_bit_cast(u32, f);
    u32 r = (x + 0x7fffu + ((x >> 16) & 1u)) >> 16;
    return (u16)r;
}
__device__ __forceinline__ float bflo(u32 v) {
    return __builtin_bit_cast(float, v << 16);
}
__device__ __forceinline__ float bfhi(u32 v) {
    return __builtin_bit_cast(float, v & 0xffff0000u);
}
__device__ __forceinline__ float dot8(uint4 u, float4 qa, float4 qb) {
    return bflo(u.x) * qa.x + bfhi(u.x) * qa.y + bflo(u.y) * qa.z + bfhi(u.y) * qa.w +
           bflo(u.z) * qb.x + bfhi(u.z) * qb.y + bflo(u.w) * qb.z + bfhi(u.w) * qb.w;
}
__device__ __forceinline__ void acc8(uint4 u, float* a) {
    a[0] += bflo(u.x); a[1] += bfhi(u.x); a[2] += bflo(u.y); a[3] += bfhi(u.y);
    a[4] += bflo(u.z); a[5] += bfhi(u.z); a[6] += bflo(u.w); a[7] += bfhi(u.w);
}
__device__ __forceinline__ uint4 pack8(const float* s) {
    uint4 u;
    u.x = (u32)f2bf(s[0]) | ((u32)f2bf(s[1]) << 16);
    u.y = (u32)f2bf(s[2]) | ((u32)f2bf(s[3]) << 16);
    u.z = (u32)f2bf(s[4]) | ((u32)f2bf(s[5]) << 16);
    u.w = (u32)f2bf(s[6]) | ((u32)f2bf(s[7]) << 16);
    return u;
}
__device__ __forceinline__ bf16x8 pack_bf8(float4 a, float4 b) {
    union { u16 s[8]; bf16x8 v; } u;
    u.s[0] = f2bf(a.x); u.s[1] = f2bf(a.y); u.s[2] = f2bf(a.z); u.s[3] = f2bf(a.w);
    u.s[4] = f2bf(b.x); u.s[5] = f2bf(b.y); u.s[6] = f2bf(b.z); u.s[7] = f2bf(b.w);
    return u.v;
}

// shared-memory overlay for all phases (64 KB -> 2 blocks/CU co-resident)
union SharedU {
    struct { float m_s[E_]; float h_s[E_]; float pe_s[PL_]; } gru;
    float red1[256];
    float red4[4][E_];
    float red8[8][E_];
    u16 X[64 * 512];   // 64 KB (pvocab)
};

// ---------------------------------------------------------------------------
// Phase bodies (verbatim ports of the measured 399.5us champion kernels,
// parameterized on virtual block index vb).
// ---------------------------------------------------------------------------
__device__ __forceinline__ void ph_conv(int vb, int tid,
    const float* __restrict__ tables, u16* __restrict__ t0b, u16* __restrict__ t12)
{
    int t = vb / 4000;
    int c = (vb % 4000) * 256 + tid;
    const float* src = tables + (size_t)t * NW_ * E_ + (size_t)c * 8;
    float4 a = *(const float4*)src;
    float4 b = *(const float4*)(src + 4);
    float s[8] = {a.x, a.y, a.z, a.w, b.x, b.y, b.z, b.w};
    uint4 u = pack8(s);
    if (t == 0) {
        *(uint4*)(t0b + (size_t)c * 8) = u;
    } else {
        int row = c >> 5, e = (c & 31) * 8;
        *(uint4*)(t12 + (size_t)row * 512 + (t - 1) * 256 + e) = u;
    }
}

__device__ __forceinline__ void ph_gru(int b, int tid, SharedU& su,
    const float* __restrict__ tables, const float* __restrict__ Wih,
    const float* __restrict__ Whh, const float* __restrict__ bih,
    const float* __restrict__ bhh, const float* __restrict__ Wp,
    const float* __restrict__ bp, const int* __restrict__ y,
    const float* __restrict__ h_, const float* __restrict__ pe,
    float* __restrict__ q0, float* __restrict__ enc, float* __restrict__ outh)
{
    int t = tid;
    __syncthreads();
    int yb = y[b];
    su.gru.m_s[t] = tables[(size_t)NW_ * E_ + (size_t)yb * E_ + t];  // row 0 is zero
    su.gru.h_s[t] = h_[b * E_ + t];
    if (t < PL_) su.gru.pe_s[t] = pe[b * PL_ + t];
    __syncthreads();

    float g_i[3], g_h[3];
#pragma unroll
    for (int g = 0; g < 3; g++) {
        int j = g * E_ + t;
        float ai = bih[j], ah = bhh[j];
        const float4* wi = (const float4*)(Wih + (size_t)j * E_);
        const float4* wh = (const float4*)(Whh + (size_t)j * E_);
#pragma unroll 8
        for (int e = 0; e < E_ / 4; e++) {
            float4 a = wi[e], c = wh[e];
            ai += a.x * su.gru.m_s[4 * e] + a.y * su.gru.m_s[4 * e + 1] +
                  a.z * su.gru.m_s[4 * e + 2] + a.w * su.gru.m_s[4 * e + 3];
            ah += c.x * su.gru.h_s[4 * e] + c.y * su.gru.h_s[4 * e + 1] +
                  c.z * su.gru.h_s[4 * e + 2] + c.w * su.gru.h_s[4 * e + 3];
        }
        g_i[g] = ai; g_h[g] = ah;
    }
    float r = 1.f / (1.f + expf(-(g_i[0] + g_h[0])));
    float z = 1.f / (1.f + expf(-(g_i[1] + g_h[1])));
    float n = tanhf(g_i[2] + r * g_h[2]);
    float hv = (1.f - z) * n + z * su.gru.h_s[t];
    q0[b * E_ + t] = hv;
    outh[b * E_ + t] = hv;

    float ea = bp[t];
    const float4* wp = (const float4*)(Wp + (size_t)t * PL_);
#pragma unroll 8
    for (int p = 0; p < PL_ / 4; p++) {
        float4 a = wp[p];
        ea += a.x * su.gru.pe_s[4 * p] + a.y * su.gru.pe_s[4 * p + 1] +
              a.z * su.gru.pe_s[4 * p + 2] + a.w * su.gru.pe_s[4 * p + 3];
    }
    enc[b * E_ + t] = ea;
}

__device__ __forceinline__ void ph_scores0(int vb, int tid,
    const u16* __restrict__ t0b, const int* __restrict__ ctx,
    const float* __restrict__ q, float* __restrict__ p_ws)
{
    int grp = vb & 31, b = vb >> 5;
    int lane = tid & 63, w = tid >> 6;
    int h = lane >> 5, l32 = lane & 31, e0 = l32 * 8;
    float4 qa = *(const float4*)(q + b * E_ + e0);
    float4 qb = *(const float4*)(q + b * E_ + e0 + 4);
    int mbase = grp * 32 + w * 8;
    const int4* cp = (const int4*)(ctx + ((size_t)b * M_ + mbase) * 4);
    int4 c[8];
#pragma unroll
    for (int i = 0; i < 8; i++) c[i] = cp[i];

    float pa[8];
#pragma unroll
    for (int i = 0; i < 8; i++) {
        int ia = h ? c[i].y : c[i].x;
        int ib = h ? c[i].w : c[i].z;
        uint4 ra = *(const uint4*)(t0b + (size_t)ia * E_ + e0);
        uint4 rb = *(const uint4*)(t0b + (size_t)ib * E_ + e0);
        pa[i] = dot8(ra, qa, qb) + dot8(rb, qa, qb);
    }
#pragma unroll
    for (int o = 32; o > 0; o >>= 1)
#pragma unroll
        for (int i = 0; i < 8; i++) pa[i] += __shfl_xor(pa[i], o, 64);
    if (lane == 0)
#pragma unroll
        for (int i = 0; i < 8; i++) p_ws[(size_t)b * M_ + mbase + i] = pa[i];
}

__device__ __forceinline__ void ph_soft(int b, int tid, SharedU& su,
    float* __restrict__ p_ws, const float* __restrict__ qcur,
    float* __restrict__ qnext)
{
    int t = tid;
    __syncthreads();
    float4 v = *(const float4*)(p_ws + (size_t)b * M_ + t * 4);
    float lm = fmaxf(fmaxf(v.x, v.y), fmaxf(v.z, v.w));
    su.red1[t] = lm;
    __syncthreads();
    for (int s = 128; s > 0; s >>= 1) {
        if (t < s) su.red1[t] = fmaxf(su.red1[t], su.red1[t + s]);
        __syncthreads();
    }
    float mx = su.red1[0];
    __syncthreads();
    float e0 = expf(v.x - mx), e1 = expf(v.y - mx);
    float e2 = expf(v.z - mx), e3 = expf(v.w - mx);
    su.red1[t] = e0 + e1 + e2 + e3;
    __syncthreads();
    for (int s = 128; s > 0; s >>= 1) {
        if (t < s) su.red1[t] += su.red1[t + s];
        __syncthreads();
    }
    float inv = 1.f / su.red1[0];
    float4 o = make_float4(e0 * inv, e1 * inv, e2 * inv, e3 * inv);
    *(float4*)(p_ws + (size_t)b * M_ + t * 4) = o;
    qnext[b * E_ + t] = qcur[b * E_ + t];
}

__device__ __forceinline__ void ph_mems12(int vb, int tid, SharedU& su,
    const u16* __restrict__ t12, const int* __restrict__ ctx,
    const float* __restrict__ attn0, u16* __restrict__ mems1,
    u16* __restrict__ mems2, float* __restrict__ q1)
{
    int grp = vb & 31, b = vb >> 5;
    int lane = tid & 63, w = tid >> 6;
    int h = lane >> 5, l32 = lane & 31, e0 = l32 * 8;
    int mbase = grp * 32 + w * 8;
    __syncthreads();   // protect LDS reuse across loop iterations / phases
    const int4* cp = (const int4*)(ctx + ((size_t)b * M_ + mbase) * 4);
    int4 c[8];
#pragma unroll
    for (int i = 0; i < 8; i++) c[i] = cp[i];
    float4 a01 = *(const float4*)(attn0 + (size_t)b * M_ + mbase);
    float4 a23 = *(const float4*)(attn0 + (size_t)b * M_ + mbase + 4);
    float wg[8] = {a01.x, a01.y, a01.z, a01.w, a23.x, a23.y, a23.z, a23.w};

    u16* mout = h ? mems2 : mems1;
    float o_acc[8] = {0, 0, 0, 0, 0, 0, 0, 0};
#pragma unroll
    for (int i = 0; i < 8; i++) {
        size_t off = (size_t)h * 256 + e0;
        uint4 r0 = *(const uint4*)(t12 + (size_t)c[i].x * 512 + off);
        uint4 r1 = *(const uint4*)(t12 + (size_t)c[i].y * 512 + off);
        uint4 r2 = *(const uint4*)(t12 + (size_t)c[i].z * 512 + off);
        uint4 r3 = *(const uint4*)(t12 + (size_t)c[i].w * 512 + off);
        float acc[8] = {0, 0, 0, 0, 0, 0, 0, 0};
        acc8(r0, acc); acc8(r1, acc); acc8(r2, acc); acc8(r3, acc);
        *(uint4*)(mout + ((size_t)(b * M_ + mbase + i)) * 256 + e0) = pack8(acc);
        if (h == 0) {
            float wgt = wg[i];
#pragma unroll
            for (int j = 0; j < 8; j++) o_acc[j] += wgt * acc[j];
        }
    }
    if (h == 0)
#pragma unroll
        for (int j = 0; j < 8; j++) su.red4[w][e0 + j] = o_acc[j];
    __syncthreads();
    int t = tid;
    float s = su.red4[0][t] + su.red4[1][t] + su.red4[2][t] + su.red4[3][t];
    atomicAdd(q1 + b * E_ + t, s);
}

template <int MODE>
__device__ __forceinline__ void ph_sscores(int vb, int tid,
    const u16* __restrict__ mems, const float* __restrict__ q,
    const float* __restrict__ enc, float* __restrict__ p_ws,
    float* __restrict__ out)
{
    int grp = vb & 31, b = vb >> 5;
    int lane = tid & 63, w = tid >> 6;
    int h = lane >> 5, l32 = lane & 31, e0 = l32 * 8;
    float4 qa = *(const float4*)(q + b * E_ + e0);
    float4 qb = *(const float4*)(q + b * E_ + e0 + 4);
    float4 ea4 = make_float4(0, 0, 0, 0), eb4 = make_float4(0, 0, 0, 0);
    if (MODE == 1) {
        float4 ev = *(const float4*)(enc + b * E_ + e0);
        float4 ew = *(const float4*)(enc + b * E_ + e0 + 4);
        ea4 = make_float4(qa.x * ev.x, qa.y * ev.y, qa.z * ev.z, qa.w * ev.w);
        eb4 = make_float4(qb.x * ew.x, qb.y * ew.y, qb.z * ew.z, qb.w * ew.w);
    }
    int mbase = grp * 32 + w * 8;
    float pa[4], pr[4];
#pragma unroll
    for (int i = 0; i < 4; i++) {
        int m = mbase + 2 * i + h;
        uint4 r = *(const uint4*)(mems + ((size_t)(b * M_ + m)) * 256 + e0);
        pa[i] = dot8(r, qa, qb);
        if (MODE == 1) pr[i] = dot8(r, ea4, eb4);
    }
#pragma unroll
    for (int o = 16; o > 0; o >>= 1)
#pragma unroll
        for (int i = 0; i < 4; i++) {
            pa[i] += __shfl_xor(pa[i], o, 64);
            if (MODE == 1) pr[i] += __shfl_xor(pr[i], o, 64);
        }
    if (l32 == 0) {
#pragma unroll
        for (int i = 0; i < 4; i++) {
            int m = mbase + 2 * i + h;
            if (MODE == 2) out[P_OFF + (size_t)b * M_ + m] = pa[i];
            else           p_ws[(size_t)b * M_ + m] = pa[i];
            if (MODE == 1) out[PR_OFF + (size_t)b * M_ + m] = pr[i];
        }
    }
}

__device__ __forceinline__ void ph_so(int vb, int tid, SharedU& su,
    const u16* __restrict__ mems, const float* __restrict__ attn,
    float* __restrict__ qnext)
{
    int ch = vb & 7, b = vb >> 3;
    int lane = tid & 63, w = tid >> 6;
    int h = lane >> 5, l32 = lane & 31, e0 = l32 * 8;
    int m0 = ch * 128;
    __syncthreads();
    float acc[8] = {0, 0, 0, 0, 0, 0, 0, 0};
    for (int i = 0; i < 16; i++) {
        int m = m0 + i * 8 + w * 2 + h;
        float wgt = attn[(size_t)b * M_ + m];
        uint4 r = *(const uint4*)(mems + ((size_t)(b * M_ + m)) * 256 + e0);
        acc[0] += wgt * bflo(r.x); acc[1] += wgt * bfhi(r.x);
        acc[2] += wgt * bflo(r.y); acc[3] += wgt * bfhi(r.y);
        acc[4] += wgt * bflo(r.z); acc[5] += wgt * bfhi(r.z);
        acc[6] += wgt * bflo(r.w); acc[7] += wgt * bfhi(r.w);
    }
    int hw = tid >> 5;
#pragma unroll
    for (int j = 0; j < 8; j++) su.red8[hw][e0 + j] = acc[j];
    __syncthreads();
    int t = tid;
    float s = 0.f;
#pragma unroll
    for (int k = 0; k < 8; k++) s += su.red8[k][t];
    atomicAdd(qnext + b * E_ + t, s);
}

__device__ __forceinline__ void ph_pvocab(int vbp, int tid, SharedU& su,
    const float* __restrict__ Wv, const float* __restrict__ bv,
    const float* __restrict__ q0, const float* __restrict__ q1,
    float* __restrict__ out)
{
    int t = tid;
    __syncthreads();   // previous users of su must be done before X overwrite
#pragma unroll
    for (int it = 0; it < 16; it++) {
        int id = t + it * 256;
        int bb = id >> 6, c = id & 63;
        float v[8];
        if (c < 32) {
            const float* s = q0 + bb * E_ + c * 8;
#pragma unroll
            for (int j = 0; j < 8; j++) v[j] = s[j];
        } else {
            const float* s1 = q1 + bb * E_ + (c - 32) * 8;
            const float* s0 = q0 + bb * E_ + (c - 32) * 8;
#pragma unroll
            for (int j = 0; j < 8; j++) v[j] = s1[j] - s0[j];
        }
        uint4 uv = pack8(v);
        *(uint4*)(&su.X[bb * 512 + ((c ^ (bb & 7)) << 3)]) = uv;
    }
    __syncthreads();

    int lane = t & 63, w = t >> 6;
    int l15 = lane & 15, quad = lane >> 4;
    int n = vbp * 64 + w * 16 + l15;
    const float4* wp = (const float4*)(Wv + (size_t)n * 512);
    f32x4 acc[4];
#pragma unroll
    for (int mt = 0; mt < 4; mt++) acc[mt] = f32x4{0.f, 0.f, 0.f, 0.f};

#pragma unroll
    for (int half = 0; half < 2; half++) {
        float4 wv[8][2];
#pragma unroll
        for (int k8 = 0; k8 < 8; k8++) {
            int ks = half * 8 + k8;
            wv[k8][0] = wp[ks * 8 + quad * 2];
            wv[k8][1] = wp[ks * 8 + quad * 2 + 1];
        }
#pragma unroll
        for (int k8 = 0; k8 < 8; k8++) {
            int ks = half * 8 + k8;
            bf16x8 bfr = pack_bf8(wv[k8][0], wv[k8][1]);
#pragma unroll
            for (int mt = 0; mt < 4; mt++) {
                int m = mt * 16 + l15;
                int c = ks * 4 + quad;
                bf16x8 a = *(const bf16x8*)(&su.X[m * 512 + ((c ^ (m & 7)) << 3)]);
                acc[mt] = __builtin_amdgcn_mfma_f32_16x16x32_bf16(a, bfr, acc[mt], 0, 0, 0);
            }
        }
    }
    float bvv = bv[n];
#pragma unroll
    for (int mt = 0; mt < 4; mt++) {
#pragma unroll
        for (int j = 0; j < 4; j++) {
            int m = mt * 16 + quad * 4 + j;
            out[PV_OFF + (size_t)m * 32000 + n] = acc[mt][j] + bvv;
        }
    }
}

// ---------------------------------------------------------------------------
// The mega-kernel: all phases, separated by grid.sync().
// ---------------------------------------------------------------------------
__global__ __launch_bounds__(256, 2) void mega(
    const float* __restrict__ tables, const float* __restrict__ Wih,
    const float* __restrict__ Whh, const float* __restrict__ bih,
    const float* __restrict__ bhh, const float* __restrict__ Wp,
    const float* __restrict__ bp, const float* __restrict__ Wv,
    const float* __restrict__ bv, const int* __restrict__ ctx,
    const int* __restrict__ y, const float* __restrict__ h_,
    const float* __restrict__ pe, float* __restrict__ out,
    u16* __restrict__ t0b, u16* __restrict__ t12,
    u16* __restrict__ mems1, u16* __restrict__ mems2,
    float* __restrict__ p_ws, float* __restrict__ q, float* __restrict__ enc)
{
    cg::grid_group grid = cg::this_grid();
    __shared__ SharedU su;
    int bid = blockIdx.x, G = gridDim.x, tid = threadIdx.x;

    // P0: table conversion (blocks [0, G-64)) + GRU/profile-enc (last 64 blocks)
    int gru0 = G - 64;
    if (bid >= gru0) {
        ph_gru(bid - gru0, tid, su, tables, Wih, Whh, bih, bhh, Wp, bp, y, h_, pe,
               q, enc, out + H_OFF);
    } else {
        for (int vb = bid; vb < 12000; vb += gru0)
            ph_conv(vb, tid, tables, t0b, t12);
    }
    grid.sync();
    // P1: hop-0 scores
    for (int vb = bid; vb < 2048; vb += G) ph_scores0(vb, tid, t0b, ctx, q, p_ws);
    grid.sync();
    // P2: softmax0 + q1 = q0
    if (bid < 64) ph_soft(bid, tid, su, p_ws, q, q + 16384);
    grid.sync();
    // P3: build mems1/mems2 + fused o0 -> q1
    for (int vb = bid; vb < 2048; vb += G)
        ph_mems12(vb, tid, su, t12, ctx, p_ws, mems1, mems2, q + 16384);
    grid.sync();
    // P4: hop-1 scores (+ p_resto)
    for (int vb = bid; vb < 2048; vb += G)
        ph_sscores<1>(vb, tid, mems1, q + 16384, enc, p_ws, out);
    grid.sync();
    // P5: softmax1 + q2 = q1
    if (bid < 64) ph_soft(bid, tid, su, p_ws, q + 16384, q + 32768);
    grid.sync();
    // P6: o1 -> q2
    for (int vb = bid; vb < 512; vb += G)
        ph_so(vb, tid, su, mems2, p_ws, q + 32768);
    grid.sync();
    // P7: hop-2 scores -> p out, and p_vocab head (independent block ranges)
    for (int vb = bid; vb < 2048 + 500; vb += G) {
        if (vb < 2048) ph_sscores<2>(vb, tid, mems2, q + 32768, enc, p_ws, out);
        else           ph_pvocab(vb - 2048, tid, su, Wv, bv, q, q + 16384, out);
    }
}

// ---------------------------------------------------------------------------
extern "C" void kernel_launch(void* const* d_in, const int* in_sizes, int n_in,
                              void* d_out, int out_size, void* d_ws, size_t ws_size,
                              hipStream_t stream)
{
    const float* tables = (const float*)d_in[0];
    const float* Wih = (const float*)d_in[1];
    const float* Whh = (const float*)d_in[2];
    const float* bih = (const float*)d_in[3];
    const float* bhh = (const float*)d_in[4];
    const float* Wp  = (const float*)d_in[5];
    const float* bp  = (const float*)d_in[6];
    const float* Wv  = (const float*)d_in[7];
    const float* bv  = (const float*)d_in[8];
    const int* ctx = (const int*)d_in[9];
    const int* y   = (const int*)d_in[10];
    const float* h_  = (const float*)d_in[11];
    const float* pe  = (const float*)d_in[12];
    float* out = (float*)d_out;

    // ws layout (identical to the 399.5us champion)
    float* Wf   = (float*)d_ws;
    float* q    = Wf;                              // q0/q1/q2 at 0/16384/32768
    float* enc  = Wf + 65536;
    float* p_ws = Wf + 81920;                      // scores then attn in-place
    char* base  = (char*)d_ws + 589824;
    u16* t0b    = (u16*)base;                      // 32000*256
    u16* t12    = (u16*)(base + 16384000);         // 32000*512
    u16* mems1  = (u16*)(base + 16384000 + 32768000);
    u16* mems2  = (u16*)(base + 16384000 + 32768000 + 33554432);

    // co-resident grid size (grid-size-agnostic kernel; 2 blocks/CU target)
    int nb = 0;
    hipOccupancyMaxActiveBlocksPerMultiprocessor(&nb, mega, 256, 0);
    if (nb < 1) nb = 1;
    int G = nb * 256;
    if (G > 512) G = 512;
    if (G < 128) G = 128;

    void* args[] = {
        (void*)&tables, (void*)&Wih, (void*)&Whh, (void*)&bih, (void*)&bhh,
        (void*)&Wp, (void*)&bp, (void*)&Wv, (void*)&bv, (void*)&ctx,
        (void*)&y, (void*)&h_, (void*)&pe, (void*)&out,
        (void*)&t0b, (void*)&t12, (void*)&mems1, (void*)&mems2,
        (void*)&p_ws, (void*)&q, (void*)&enc
    };
    hipLaunchCooperativeKernel((void*)mega, dim3(G), dim3(256), args, 0, stream);
}

// Round 5
// 370.308 us; speedup vs baseline: 1.6196x; 1.6196x over previous
//
#include <hip/hip_runtime.h>
#include <cstdint>

#define B_ 64
#define M_ 1024
#define F_ 4
#define E_ 256
#define NW_ 32000
#define PL_ 128

// output element offsets (fp32 elements)
#define P_OFF   0
#define PV_OFF  65536
#define PR_OFF  2113536
#define H_OFF   2179072

typedef unsigned short u16;
typedef unsigned int u32;

typedef __bf16 bf16x8 __attribute__((ext_vector_type(8)));
typedef float f32x4 __attribute__((ext_vector_type(4)));

__device__ __forceinline__ u16 f2bf(float f) {
    u32 x = __builtin_bit_cast(u32, f);
    u32 r = (x + 0x7fffu + ((x >> 16) & 1u)) >> 16;
    return (u16)r;
}
__device__ __forceinline__ float bflo(u32 v) {
    return __builtin_bit_cast(float, v << 16);
}
__device__ __forceinline__ float bfhi(u32 v) {
    return __builtin_bit_cast(float, v & 0xffff0000u);
}
__device__ __forceinline__ float dot8(uint4 u, float4 qa, float4 qb) {
    return bflo(u.x) * qa.x + bfhi(u.x) * qa.y + bflo(u.y) * qa.z + bfhi(u.y) * qa.w +
           bflo(u.z) * qb.x + bfhi(u.z) * qb.y + bflo(u.w) * qb.z + bfhi(u.w) * qb.w;
}
__device__ __forceinline__ void acc8(uint4 u, float* a) {
    a[0] += bflo(u.x); a[1] += bfhi(u.x); a[2] += bflo(u.y); a[3] += bfhi(u.y);
    a[4] += bflo(u.z); a[5] += bfhi(u.z); a[6] += bflo(u.w); a[7] += bfhi(u.w);
}
__device__ __forceinline__ uint4 pack8(const float* s) {
    uint4 u;
    u.x = (u32)f2bf(s[0]) | ((u32)f2bf(s[1]) << 16);
    u.y = (u32)f2bf(s[2]) | ((u32)f2bf(s[3]) << 16);
    u.z = (u32)f2bf(s[4]) | ((u32)f2bf(s[5]) << 16);
    u.w = (u32)f2bf(s[6]) | ((u32)f2bf(s[7]) << 16);
    return u;
}
__device__ __forceinline__ bf16x8 pack_bf8(float4 a, float4 b) {
    union { u16 s[8]; bf16x8 v; } u;
    u.s[0] = f2bf(a.x); u.s[1] = f2bf(a.y); u.s[2] = f2bf(a.z); u.s[3] = f2bf(a.w);
    u.s[4] = f2bf(b.x); u.s[5] = f2bf(b.y); u.s[6] = f2bf(b.z); u.s[7] = f2bf(b.w);
    return u.v;
}

// ---------------------------------------------------------------------------
// L1: fused GRU (blocks 0..63, critical path first) + table conversion
// (blocks 64..12063).  Bodies identical to the measured champion kernels.
// ---------------------------------------------------------------------------
__global__ __launch_bounds__(256) void k_convgru(
    const float* __restrict__ tables, const float* __restrict__ Wih,
    const float* __restrict__ Whh, const float* __restrict__ bih,
    const float* __restrict__ bhh, const float* __restrict__ Wp,
    const float* __restrict__ bp, const int* __restrict__ y,
    const float* __restrict__ h_, const float* __restrict__ pe,
    float* __restrict__ q0, float* __restrict__ enc, float* __restrict__ outh,
    u16* __restrict__ t0b, u16* __restrict__ t12)
{
    int vb = blockIdx.x, tid = threadIdx.x;
    if (vb >= 64) {
        // ---- conversion: tables 0..2 fp32 -> bf16 (t0b, t12 interleaved) ----
        int cvb = vb - 64;
        int t = cvb / 4000;
        int c = (cvb % 4000) * 256 + tid;
        const float* src = tables + (size_t)t * NW_ * E_ + (size_t)c * 8;
        float4 a = *(const float4*)src;
        float4 b = *(const float4*)(src + 4);
        float s[8] = {a.x, a.y, a.z, a.w, b.x, b.y, b.z, b.w};
        uint4 u = pack8(s);
        if (t == 0) {
            *(uint4*)(t0b + (size_t)c * 8) = u;
        } else {
            int row = c >> 5, e = (c & 31) * 8;
            *(uint4*)(t12 + (size_t)row * 512 + (t - 1) * 256 + e) = u;
        }
        return;
    }
    // ---- GRU step + profile encoding ----
    int b = vb, t = tid;
    __shared__ float m_s[E_], h_s[E_], pe_s[PL_];
    int yb = y[b];
    m_s[t] = tables[(size_t)NW_ * E_ + (size_t)yb * E_ + t];  // row 0 is zero
    h_s[t] = h_[b * E_ + t];
    if (t < PL_) pe_s[t] = pe[b * PL_ + t];
    __syncthreads();

    float g_i[3], g_h[3];
#pragma unroll
    for (int g = 0; g < 3; g++) {
        int j = g * E_ + t;
        float ai = bih[j], ah = bhh[j];
        const float4* wi = (const float4*)(Wih + (size_t)j * E_);
        const float4* wh = (const float4*)(Whh + (size_t)j * E_);
#pragma unroll 8
        for (int e = 0; e < E_ / 4; e++) {
            float4 a = wi[e], c = wh[e];
            ai += a.x * m_s[4 * e] + a.y * m_s[4 * e + 1] +
                  a.z * m_s[4 * e + 2] + a.w * m_s[4 * e + 3];
            ah += c.x * h_s[4 * e] + c.y * h_s[4 * e + 1] +
                  c.z * h_s[4 * e + 2] + c.w * h_s[4 * e + 3];
        }
        g_i[g] = ai; g_h[g] = ah;
    }
    float r = 1.f / (1.f + expf(-(g_i[0] + g_h[0])));
    float z = 1.f / (1.f + expf(-(g_i[1] + g_h[1])));
    float n = tanhf(g_i[2] + r * g_h[2]);
    float hv = (1.f - z) * n + z * h_s[t];
    q0[b * E_ + t] = hv;
    outh[b * E_ + t] = hv;

    float ea = bp[t];
    const float4* wp = (const float4*)(Wp + (size_t)t * PL_);
#pragma unroll 8
    for (int p = 0; p < PL_ / 4; p++) {
        float4 a = wp[p];
        ea += a.x * pe_s[4 * p] + a.y * pe_s[4 * p + 1] +
              a.z * pe_s[4 * p + 2] + a.w * pe_s[4 * p + 3];
    }
    enc[b * E_ + t] = ea;
}

// ---------------------------------------------------------------------------
// K2: hop-0 scores from bf16 table t0b.  grid (32,64) x 256.  (champion)
// ---------------------------------------------------------------------------
__global__ __launch_bounds__(256) void k_scores0(
    const u16* __restrict__ t0b, const int* __restrict__ ctx,
    const float* __restrict__ q, float* __restrict__ p_ws)
{
    int b = blockIdx.y, grp = blockIdx.x;
    int lane = threadIdx.x & 63, w = threadIdx.x >> 6;
    int h = lane >> 5, l32 = lane & 31, e0 = l32 * 8;
    float4 qa = *(const float4*)(q + b * E_ + e0);
    float4 qb = *(const float4*)(q + b * E_ + e0 + 4);
    int mbase = grp * 32 + w * 8;
    const int4* cp = (const int4*)(ctx + ((size_t)b * M_ + mbase) * 4);
    int4 c[8];
#pragma unroll
    for (int i = 0; i < 8; i++) c[i] = cp[i];

    float pa[8];
#pragma unroll
    for (int i = 0; i < 8; i++) {
        int ia = h ? c[i].y : c[i].x;
        int ib = h ? c[i].w : c[i].z;
        uint4 ra = *(const uint4*)(t0b + (size_t)ia * E_ + e0);
        uint4 rb = *(const uint4*)(t0b + (size_t)ib * E_ + e0);
        pa[i] = dot8(ra, qa, qb) + dot8(rb, qa, qb);
    }
#pragma unroll
    for (int o = 32; o > 0; o >>= 1)
#pragma unroll
        for (int i = 0; i < 8; i++) pa[i] += __shfl_xor(pa[i], o, 64);
    if (lane == 0)
#pragma unroll
        for (int i = 0; i < 8; i++) p_ws[(size_t)b * M_ + mbase + i] = pa[i];
}

// ---------------------------------------------------------------------------
// K3: softmax over m (in-place) + qnext = qcur.  64 blocks x 256.  (champion)
// ---------------------------------------------------------------------------
__global__ __launch_bounds__(256) void k_soft(
    float* __restrict__ p_ws, const float* __restrict__ qcur,
    float* __restrict__ qnext)
{
    int b = blockIdx.x, t = threadIdx.x;
    __shared__ float red[256];
    float4 v = *(const float4*)(p_ws + (size_t)b * M_ + t * 4);
    float lm = fmaxf(fmaxf(v.x, v.y), fmaxf(v.z, v.w));
    red[t] = lm;
    __syncthreads();
    for (int s = 128; s > 0; s >>= 1) {
        if (t < s) red[t] = fmaxf(red[t], red[t + s]);
        __syncthreads();
    }
    float mx = red[0];
    __syncthreads();
    float e0 = expf(v.x - mx), e1 = expf(v.y - mx);
    float e2 = expf(v.z - mx), e3 = expf(v.w - mx);
    red[t] = e0 + e1 + e2 + e3;
    __syncthreads();
    for (int s = 128; s > 0; s >>= 1) {
        if (t < s) red[t] += red[t + s];
        __syncthreads();
    }
    float inv = 1.f / red[0];
    float4 o = make_float4(e0 * inv, e1 * inv, e2 * inv, e3 * inv);
    *(float4*)(p_ws + (size_t)b * M_ + t * 4) = o;
    qnext[b * E_ + t] = qcur[b * E_ + t];
}

// ---------------------------------------------------------------------------
// K4: build mems1/mems2 (bf16) from interleaved t12, fused o0 accum.
// grid (32,64) x 256.  (champion)
// ---------------------------------------------------------------------------
__global__ __launch_bounds__(256) void k_mems12(
    const u16* __restrict__ t12, const int* __restrict__ ctx,
    const float* __restrict__ attn0, u16* __restrict__ mems1,
    u16* __restrict__ mems2, float* __restrict__ q1)
{
    int b = blockIdx.y, grp = blockIdx.x;
    int lane = threadIdx.x & 63, w = threadIdx.x >> 6;
    int h = lane >> 5, l32 = lane & 31, e0 = l32 * 8;
    int mbase = grp * 32 + w * 8;
    const int4* cp = (const int4*)(ctx + ((size_t)b * M_ + mbase) * 4);
    int4 c[8];
#pragma unroll
    for (int i = 0; i < 8; i++) c[i] = cp[i];
    float4 a01 = *(const float4*)(attn0 + (size_t)b * M_ + mbase);
    float4 a23 = *(const float4*)(attn0 + (size_t)b * M_ + mbase + 4);
    float wg[8] = {a01.x, a01.y, a01.z, a01.w, a23.x, a23.y, a23.z, a23.w};

    u16* mout = h ? mems2 : mems1;
    float o_acc[8] = {0, 0, 0, 0, 0, 0, 0, 0};
#pragma unroll
    for (int i = 0; i < 8; i++) {
        size_t off = (size_t)h * 256 + e0;
        uint4 r0 = *(const uint4*)(t12 + (size_t)c[i].x * 512 + off);
        uint4 r1 = *(const uint4*)(t12 + (size_t)c[i].y * 512 + off);
        uint4 r2 = *(const uint4*)(t12 + (size_t)c[i].z * 512 + off);
        uint4 r3 = *(const uint4*)(t12 + (size_t)c[i].w * 512 + off);
        float acc[8] = {0, 0, 0, 0, 0, 0, 0, 0};
        acc8(r0, acc); acc8(r1, acc); acc8(r2, acc); acc8(r3, acc);
        *(uint4*)(mout + ((size_t)(b * M_ + mbase + i)) * 256 + e0) = pack8(acc);
        if (h == 0) {
            float wgt = wg[i];
#pragma unroll
            for (int j = 0; j < 8; j++) o_acc[j] += wgt * acc[j];
        }
    }
    __shared__ float red[4][E_];
    if (h == 0)
#pragma unroll
        for (int j = 0; j < 8; j++) red[w][e0 + j] = o_acc[j];
    __syncthreads();
    int t = threadIdx.x;
    float s = red[0][t] + red[1][t] + red[2][t] + red[3][t];
    atomicAdd(q1 + b * E_ + t, s);
}

// ---------------------------------------------------------------------------
// L5: fused p_vocab (blocks 0..249, starts immediately) + hop-1 streaming
// scores with p_resto (blocks 250..2297).  Bodies identical to champion.
// ---------------------------------------------------------------------------
__global__ __launch_bounds__(256) void k_ss1pv(
    const u16* __restrict__ mems, const float* __restrict__ q1v,
    const float* __restrict__ enc, float* __restrict__ p_ws,
    float* __restrict__ out, const float* __restrict__ Wv,
    const float* __restrict__ bv, const float* __restrict__ q0)
{
    if (blockIdx.x >= 250) {
        // ---- sscores MODE 1 ----
        int vb = blockIdx.x - 250;
        int grp = vb & 31, b = vb >> 5;
        int lane = threadIdx.x & 63, w = threadIdx.x >> 6;
        int h = lane >> 5, l32 = lane & 31, e0 = l32 * 8;
        float4 qa = *(const float4*)(q1v + b * E_ + e0);
        float4 qb = *(const float4*)(q1v + b * E_ + e0 + 4);
        float4 ev = *(const float4*)(enc + b * E_ + e0);
        float4 ew = *(const float4*)(enc + b * E_ + e0 + 4);
        float4 ea4 = make_float4(qa.x * ev.x, qa.y * ev.y, qa.z * ev.z, qa.w * ev.w);
        float4 eb4 = make_float4(qb.x * ew.x, qb.y * ew.y, qb.z * ew.z, qb.w * ew.w);
        int mbase = grp * 32 + w * 8;
        float pa[4], pr[4];
#pragma unroll
        for (int i = 0; i < 4; i++) {
            int m = mbase + 2 * i + h;
            uint4 r = *(const uint4*)(mems + ((size_t)(b * M_ + m)) * 256 + e0);
            pa[i] = dot8(r, qa, qb);
            pr[i] = dot8(r, ea4, eb4);
        }
#pragma unroll
        for (int o = 16; o > 0; o >>= 1)
#pragma unroll
            for (int i = 0; i < 4; i++) {
                pa[i] += __shfl_xor(pa[i], o, 64);
                pr[i] += __shfl_xor(pr[i], o, 64);
            }
        if (l32 == 0) {
#pragma unroll
            for (int i = 0; i < 4; i++) {
                int m = mbase + 2 * i + h;
                p_ws[(size_t)b * M_ + m] = pa[i];
                out[PR_OFF + (size_t)b * M_ + m] = pr[i];
            }
        }
        return;
    }
    // ---- pvocab ----
    __shared__ u16 X[64 * 512];  // 64KB
    int t = threadIdx.x;
#pragma unroll
    for (int it = 0; it < 16; it++) {
        int id = t + it * 256;
        int bb = id >> 6, c = id & 63;
        float v[8];
        if (c < 32) {
            const float* s = q0 + bb * E_ + c * 8;
#pragma unroll
            for (int j = 0; j < 8; j++) v[j] = s[j];
        } else {
            const float* s1 = q1v + bb * E_ + (c - 32) * 8;
            const float* s0 = q0 + bb * E_ + (c - 32) * 8;
#pragma unroll
            for (int j = 0; j < 8; j++) v[j] = s1[j] - s0[j];
        }
        uint4 uv = pack8(v);
        *(uint4*)(&X[bb * 512 + ((c ^ (bb & 7)) << 3)]) = uv;
    }
    __syncthreads();

    int lane = t & 63, w = t >> 6;
    int n0 = blockIdx.x * 128 + w * 32;
    int l15 = lane & 15, quad = lane >> 4;
    f32x4 acc[4][2];
#pragma unroll
    for (int mt = 0; mt < 4; mt++)
#pragma unroll
        for (int nt = 0; nt < 2; nt++)
            acc[mt][nt] = f32x4{0.f, 0.f, 0.f, 0.f};

    for (int ks = 0; ks < 16; ks++) {
        bf16x8 a[4], bfr[2];
#pragma unroll
        for (int mt = 0; mt < 4; mt++) {
            int m = mt * 16 + l15;
            int c = ks * 4 + quad;
            a[mt] = *(const bf16x8*)(&X[m * 512 + ((c ^ (m & 7)) << 3)]);
        }
#pragma unroll
        for (int nt = 0; nt < 2; nt++) {
            int n = n0 + nt * 16 + l15;
            const float4* wp = (const float4*)(Wv + (size_t)n * 512 + ks * 32 + quad * 8);
            bfr[nt] = pack_bf8(wp[0], wp[1]);
        }
#pragma unroll
        for (int mt = 0; mt < 4; mt++)
#pragma unroll
            for (int nt = 0; nt < 2; nt++)
                acc[mt][nt] = __builtin_amdgcn_mfma_f32_16x16x32_bf16(
                    a[mt], bfr[nt], acc[mt][nt], 0, 0, 0);
    }
#pragma unroll
    for (int nt = 0; nt < 2; nt++) {
        int n = n0 + nt * 16 + l15;
        float bvv = bv[n];
#pragma unroll
        for (int mt = 0; mt < 4; mt++) {
#pragma unroll
            for (int j = 0; j < 4; j++) {
                int m = mt * 16 + quad * 4 + j;
                out[PV_OFF + (size_t)m * 32000 + n] = acc[mt][nt][j] + bvv;
            }
        }
    }
}

// ---------------------------------------------------------------------------
// K5 (MODE 2): hop-2 streaming scores -> p out.  grid (32,64) x 256. (champion)
// ---------------------------------------------------------------------------
__global__ __launch_bounds__(256) void k_sscores2(
    const u16* __restrict__ mems, const float* __restrict__ q,
    float* __restrict__ out)
{
    int b = blockIdx.y, grp = blockIdx.x;
    int lane = threadIdx.x & 63, w = threadIdx.x >> 6;
    int h = lane >> 5, l32 = lane & 31, e0 = l32 * 8;
    float4 qa = *(const float4*)(q + b * E_ + e0);
    float4 qb = *(const float4*)(q + b * E_ + e0 + 4);
    int mbase = grp * 32 + w * 8;
    float pa[4];
#pragma unroll
    for (int i = 0; i < 4; i++) {
        int m = mbase + 2 * i + h;
        uint4 r = *(const uint4*)(mems + ((size_t)(b * M_ + m)) * 256 + e0);
        pa[i] = dot8(r, qa, qb);
    }
#pragma unroll
    for (int o = 16; o > 0; o >>= 1)
#pragma unroll
        for (int i = 0; i < 4; i++) pa[i] += __shfl_xor(pa[i], o, 64);
    if (l32 == 0) {
#pragma unroll
        for (int i = 0; i < 4; i++) {
            int m = mbase + 2 * i + h;
            out[P_OFF + (size_t)b * M_ + m] = pa[i];
        }
    }
}

// ---------------------------------------------------------------------------
// K6: streaming o = sum_m attn[m]*mems[m,:] -> atomic into qnext.
// grid (8,64) x 256.  (champion)
// ---------------------------------------------------------------------------
__global__ __launch_bounds__(256) void k_so(
    const u16* __restrict__ mems, const float* __restrict__ attn,
    float* __restrict__ qnext)
{
    int b = blockIdx.y, ch = blockIdx.x;
    int lane = threadIdx.x & 63, w = threadIdx.x >> 6;
    int h = lane >> 5, l32 = lane & 31, e0 = l32 * 8;
    int m0 = ch * 128;
    float acc[8] = {0, 0, 0, 0, 0, 0, 0, 0};
    for (int i = 0; i < 16; i++) {
        int m = m0 + i * 8 + w * 2 + h;
        float wgt = attn[(size_t)b * M_ + m];
        uint4 r = *(const uint4*)(mems + ((size_t)(b * M_ + m)) * 256 + e0);
        acc[0] += wgt * bflo(r.x); acc[1] += wgt * bfhi(r.x);
        acc[2] += wgt * bflo(r.y); acc[3] += wgt * bfhi(r.y);
        acc[4] += wgt * bflo(r.z); acc[5] += wgt * bfhi(r.z);
        acc[6] += wgt * bflo(r.w); acc[7] += wgt * bfhi(r.w);
    }
    __shared__ float red[8][E_];
    int hw = threadIdx.x >> 5;
#pragma unroll
    for (int j = 0; j < 8; j++) red[hw][e0 + j] = acc[j];
    __syncthreads();
    int t = threadIdx.x;
    float s = 0.f;
#pragma unroll
    for (int k = 0; k < 8; k++) s += red[k][t];
    atomicAdd(qnext + b * E_ + t, s);
}

// ---------------------------------------------------------------------------
extern "C" void kernel_launch(void* const* d_in, const int* in_sizes, int n_in,
                              void* d_out, int out_size, void* d_ws, size_t ws_size,
                              hipStream_t stream)
{
    const float* tables = (const float*)d_in[0];
    const float* Wih = (const float*)d_in[1];
    const float* Whh = (const float*)d_in[2];
    const float* bih = (const float*)d_in[3];
    const float* bhh = (const float*)d_in[4];
    const float* Wp  = (const float*)d_in[5];
    const float* bp  = (const float*)d_in[6];
    const float* Wv  = (const float*)d_in[7];
    const float* bv  = (const float*)d_in[8];
    const int* ctx = (const int*)d_in[9];
    const int* y   = (const int*)d_in[10];
    const float* h_  = (const float*)d_in[11];
    const float* pe  = (const float*)d_in[12];
    float* out = (float*)d_out;

    // ws layout (identical to the 399.5us champion)
    float* Wf   = (float*)d_ws;
    float* q    = Wf;            // q0/q1/q2 at 0/16384/32768
    float* enc  = Wf + 65536;
    float* p_ws = Wf + 81920;    // scores then attn in-place
    char* base  = (char*)d_ws + 589824;
    u16* t0b    = (u16*)base;                      // 32000*256
    u16* t12    = (u16*)(base + 16384000);         // 32000*512
    u16* mems1  = (u16*)(base + 16384000 + 32768000);
    u16* mems2  = (u16*)(base + 16384000 + 32768000 + 33554432);

    // L1: gru (first 64 blocks) + table conversion (12000 blocks)
    k_convgru<<<12064, 256, 0, stream>>>(tables, Wih, Whh, bih, bhh, Wp, bp,
                                         y, h_, pe, q, enc, out + H_OFF,
                                         t0b, t12);
    // L2: hop-0 scores
    k_scores0<<<dim3(32, 64), 256, 0, stream>>>(t0b, ctx, q, p_ws);
    // L3: softmax0 + q1 = q0
    k_soft<<<64, 256, 0, stream>>>(p_ws, q, q + 16384);
    // L4: build mems1/mems2 + fused o0 -> q1
    k_mems12<<<dim3(32, 64), 256, 0, stream>>>(t12, ctx, p_ws, mems1, mems2,
                                               q + 16384);
    // L5: pvocab (250 blocks, first) + hop-1 scores/p_resto (2048 blocks)
    k_ss1pv<<<2298, 256, 0, stream>>>(mems1, q + 16384, enc, p_ws, out,
                                      Wv, bv, q);
    // L6: softmax1 + q2 = q1
    k_soft<<<64, 256, 0, stream>>>(p_ws, q + 16384, q + 32768);
    // L7: o1 -> q2
    k_so<<<dim3(8, 64), 256, 0, stream>>>(mems2, p_ws, q + 32768);
    // L8: hop-2 scores -> p out
    k_sscores2<<<dim3(32, 64), 256, 0, stream>>>(mems2, q + 32768, out);
}